// Round 1
// baseline (405.268 us; speedup 1.0000x reference)
//
#include <hip/hip_runtime.h>

typedef __bf16 bf16_t;
typedef __bf16 bf16x8 __attribute__((ext_vector_type(8)));
typedef float f32x4 __attribute__((ext_vector_type(4)));

#define N_PIX 4096
#define CFEAT 256
#define CKEY 32
#define NBATCH 4

// ---------------------------------------------------------------------------
// proj_kernel: Y[b][m][n] = bf16( sum_c W[m][c] * X[b][c][n] + bias[m] )
// W fp32 [M][256], X fp32 [B][256][4096], Y bf16 [B][M][4096]
// grid: (N/64, ceil(M/64), B), block 256 (4 waves; wave w -> rows w*16..w*16+15)
// ---------------------------------------------------------------------------
__global__ __launch_bounds__(256) void proj_kernel(
    const float* __restrict__ W, const float* __restrict__ bias,
    const float* __restrict__ X, bf16_t* __restrict__ Y, int M)
{
    const int lane = threadIdx.x & 63;
    const int wave = threadIdx.x >> 6;
    const int g    = lane >> 4;   // quad id 0..3
    const int ln   = lane & 15;
    const int b    = blockIdx.z;
    const int m_base = blockIdx.y * 64 + wave * 16;
    if (m_base >= M) return;
    const int n_base = blockIdx.x * 64;

    const float* Xb = X + (size_t)b * CFEAT * N_PIX;

    f32x4 acc[4];
    f32x4 zero = {0.f, 0.f, 0.f, 0.f};
#pragma unroll
    for (int nt = 0; nt < 4; ++nt) acc[nt] = zero;

    for (int k0 = 0; k0 < CFEAT; k0 += 32) {
        // A frag: W[m_base+ln][k0 + g*8 + j]  (contiguous in c)
        const float* wp = W + (size_t)(m_base + ln) * CFEAT + k0 + g * 8;
        bf16x8 afrag;
#pragma unroll
        for (int j = 0; j < 8; ++j) afrag[j] = (bf16_t)wp[j];
#pragma unroll
        for (int nt = 0; nt < 4; ++nt) {
            // B frag: X[k0+g*8+j][n_base+nt*16+ln]  (stride-N scalar loads)
            const float* xp = Xb + (size_t)(k0 + g * 8) * N_PIX + n_base + nt * 16 + ln;
            bf16x8 bfrag;
#pragma unroll
            for (int j = 0; j < 8; ++j) bfrag[j] = (bf16_t)xp[(size_t)j * N_PIX];
            acc[nt] = __builtin_amdgcn_mfma_f32_16x16x32_bf16(afrag, bfrag, acc[nt], 0, 0, 0);
        }
    }
    // Epilogue: D layout row=g*4+r, col=ln
#pragma unroll
    for (int nt = 0; nt < 4; ++nt) {
#pragma unroll
        for (int r = 0; r < 4; ++r) {
            const int m = m_base + g * 4 + r;
            const int n = n_base + nt * 16 + ln;
            Y[((size_t)b * M + m) * N_PIX + n] = (bf16_t)(acc[nt][r] + bias[m]);
        }
    }
}

// ---------------------------------------------------------------------------
// flash_kernel: out[b][c][i] = gamma * (softmax_j(q_i . k_j) @ v)[c][i] + feat[b][c][i]
// Q,K bf16 [B][32][4096]; V bf16 [B][256][4096]
// grid: (2 c-halves, 64 q-tiles, B), block 256 = 4 waves; wave owns 16 q rows.
// ---------------------------------------------------------------------------
__global__ __launch_bounds__(256) void flash_kernel(
    const bf16_t* __restrict__ Q, const bf16_t* __restrict__ K,
    const bf16_t* __restrict__ V, const float* __restrict__ features,
    const float* __restrict__ gamma, float* __restrict__ out)
{
    __shared__ __attribute__((aligned(16))) bf16_t Plds[4][16 * 64];

    const int lane = threadIdx.x & 63;
    const int wave = threadIdx.x >> 6;
    const int g    = lane >> 4;
    const int ln   = lane & 15;
    const int b    = blockIdx.z;
    const int i_base = blockIdx.y * 64 + wave * 16;   // this wave's 16 query rows
    const int c_base = blockIdx.x * 128;              // this block's 128 output channels

    const bf16_t* Qb = Q + (size_t)b * CKEY * N_PIX;
    const bf16_t* Kb = K + (size_t)b * CKEY * N_PIX;
    const bf16_t* Vb = V + (size_t)b * CFEAT * N_PIX;

    // Q A-frag (held for whole kernel): A[m=ln (=i), k=g*8+j (=ck)]
    bf16x8 qfrag;
#pragma unroll
    for (int j = 0; j < 8; ++j)
        qfrag[j] = Qb[(size_t)(g * 8 + j) * N_PIX + i_base + ln];

    f32x4 zero = {0.f, 0.f, 0.f, 0.f};
    f32x4 acc[8];
#pragma unroll
    for (int ct = 0; ct < 8; ++ct) acc[ct] = zero;
    float m_r[4], l_r[4];
#pragma unroll
    for (int r = 0; r < 4; ++r) { m_r[r] = -INFINITY; l_r[r] = 0.f; }

    for (int j0 = 0; j0 < N_PIX; j0 += 64) {
        // ---- S = Q . K_tile  -> 4 D-frags (rows = i, cols = j) ----
        f32x4 s[4];
#pragma unroll
        for (int jt = 0; jt < 4; ++jt) {
            bf16x8 kfrag;   // B[k=g*8+j (=ck), n=ln (=j)]
#pragma unroll
            for (int j = 0; j < 8; ++j)
                kfrag[j] = Kb[(size_t)(g * 8 + j) * N_PIX + j0 + jt * 16 + ln];
            s[jt] = __builtin_amdgcn_mfma_f32_16x16x32_bf16(qfrag, kfrag, zero, 0, 0, 0);
        }
        // ---- online softmax; register r holds row i_local = g*4 + r ----
        float mnew[4], alpha[4];
#pragma unroll
        for (int r = 0; r < 4; ++r) {
            float t = fmaxf(fmaxf(s[0][r], s[1][r]), fmaxf(s[2][r], s[3][r]));
#pragma unroll
            for (int msk = 1; msk < 16; msk <<= 1) t = fmaxf(t, __shfl_xor(t, msk));
            mnew[r]  = fmaxf(m_r[r], t);
            alpha[r] = __expf(m_r[r] - mnew[r]);   // exp(-inf)=0 on first tile
        }
#pragma unroll
        for (int r = 0; r < 4; ++r) {
            float rs = 0.f;
#pragma unroll
            for (int jt = 0; jt < 4; ++jt) {
                float p = __expf(s[jt][r] - mnew[r]);
                s[jt][r] = p;
                rs += p;
            }
#pragma unroll
            for (int msk = 1; msk < 16; msk <<= 1) rs += __shfl_xor(rs, msk);
            l_r[r] = l_r[r] * alpha[r] + rs;
            m_r[r] = mnew[r];
        }
        // rescale O accumulator
#pragma unroll
        for (int ct = 0; ct < 8; ++ct)
#pragma unroll
            for (int r = 0; r < 4; ++r) acc[ct][r] *= alpha[r];

        // ---- P: D-layout -> LDS -> A-layout (verified m120 pattern) ----
#pragma unroll
        for (int jt = 0; jt < 4; ++jt)
#pragma unroll
            for (int r = 0; r < 4; ++r)
                Plds[wave][(g * 4 + r) * 64 + jt * 16 + ln] = (bf16_t)s[jt][r];
        __syncthreads();   // all waves same trip count; guarantees LDS visibility
        bf16x8 pa0 = *(const bf16x8*)&Plds[wave][ln * 64 + g * 8];
        bf16x8 pa1 = *(const bf16x8*)&Plds[wave][ln * 64 + 32 + g * 8];

        // ---- O += P . V^T  (B-frag: V^T[k=j, n=c] = v[c][j], contiguous 16B) ----
#pragma unroll
        for (int ct = 0; ct < 8; ++ct) {
            const bf16_t* vp = Vb + (size_t)(c_base + ct * 16 + ln) * N_PIX + j0 + g * 8;
            bf16x8 vb0 = *(const bf16x8*)vp;
            bf16x8 vb1 = *(const bf16x8*)(vp + 32);
            acc[ct] = __builtin_amdgcn_mfma_f32_16x16x32_bf16(pa0, vb0, acc[ct], 0, 0, 0);
            acc[ct] = __builtin_amdgcn_mfma_f32_16x16x32_bf16(pa1, vb1, acc[ct], 0, 0, 0);
        }
        __syncthreads();   // protect Plds before next iteration's writes
    }

    const float gam = gamma[0];
    float invl[4];
#pragma unroll
    for (int r = 0; r < 4; ++r) invl[r] = 1.f / l_r[r];
#pragma unroll
    for (int ct = 0; ct < 8; ++ct) {
#pragma unroll
        for (int r = 0; r < 4; ++r) {
            const int i = i_base + g * 4 + r;
            const int c = c_base + ct * 16 + ln;
            const size_t idx = ((size_t)b * CFEAT + c) * N_PIX + i;
            out[idx] = gam * acc[ct][r] * invl[r] + features[idx];
        }
    }
}

// ---------------------------------------------------------------------------
extern "C" void kernel_launch(void* const* d_in, const int* in_sizes, int n_in,
                              void* d_out, int out_size, void* d_ws, size_t ws_size,
                              hipStream_t stream) {
    const float* features   = (const float*)d_in[0];
    const float* conditions = (const float*)d_in[1];
    const float* Wq  = (const float*)d_in[2];
    const float* bq  = (const float*)d_in[3];
    const float* Wk  = (const float*)d_in[4];
    const float* bk  = (const float*)d_in[5];
    const float* Wv  = (const float*)d_in[6];
    const float* bv  = (const float*)d_in[7];
    const float* gam = (const float*)d_in[8];
    float* out = (float*)d_out;

    // Workspace layout (bf16): Q [4][32][4096] | K [4][32][4096] | V [4][256][4096]
    bf16_t* Qb = (bf16_t*)d_ws;                         // 524288 elems = 1 MB
    bf16_t* Kb = Qb + (size_t)NBATCH * CKEY * N_PIX;    // 1 MB
    bf16_t* Vb = Kb + (size_t)NBATCH * CKEY * N_PIX;    // 8 MB  (total 10 MB of ws)

    proj_kernel<<<dim3(N_PIX / 64, 1, NBATCH), 256, 0, stream>>>(Wq, bq, conditions, Qb, CKEY);
    proj_kernel<<<dim3(N_PIX / 64, 1, NBATCH), 256, 0, stream>>>(Wk, bk, features,   Kb, CKEY);
    proj_kernel<<<dim3(N_PIX / 64, CFEAT / 64, NBATCH), 256, 0, stream>>>(Wv, bv, features, Vb, CFEAT);
    flash_kernel<<<dim3(2, N_PIX / 64, NBATCH), 256, 0, stream>>>(Qb, Kb, Vb, features, gam, out);
}